// Round 10
// baseline (288.299 us; speedup 1.0000x reference)
//
#include <hip/hip_runtime.h>
#include <cstdint>
#include <cstddef>
#include <cmath>

#define N_NODES 50000
#define N_EDGES 800000
#define D_FEAT 128
#define HIDDEN 128
#define N_CLASSES 40

typedef _Float16 half8 __attribute__((ext_vector_type(8)));
typedef _Float16 half4 __attribute__((ext_vector_type(4)));
typedef float f32x4 __attribute__((ext_vector_type(4)));

#define EDGE_BLOCKS 3125      // 800000 / 256
#define CVT_BLOCKS 6250       // 50000*128/4/256
#define DEG_STRIDE 16         // one counter per 64B cache line

// ---------------- combined build: [0,EDGE_BLOCKS) deg+rank ; rest: fp16 cvt + W swizzle ----------------

__global__ __launch_bounds__(256) void k_build(const int* __restrict__ dst, int* __restrict__ deg,
                                               unsigned short* __restrict__ rank,
                                               const float* __restrict__ x, _Float16* __restrict__ xh,
                                               const float* __restrict__ Wl0, const float* __restrict__ Wr0, _Float16* __restrict__ Wc0,
                                               const float* __restrict__ Wl1, const float* __restrict__ Wr1, _Float16* __restrict__ Wc1,
                                               const float* __restrict__ Wl2, const float* __restrict__ Wr2, _Float16* __restrict__ Wc2) {
    int bid = blockIdx.x;
    if (bid < EDGE_BLOCKS) {
        int e = bid * 256 + threadIdx.x;
        int r = atomicAdd(&deg[dst[e] * DEG_STRIDE], 1);
        rank[e] = (unsigned short)r;
        return;
    }
    bid -= EDGE_BLOCKS;
    if (bid < CVT_BLOCKS) {
        int i = bid * 256 + threadIdx.x;
        float4 v = *(const float4*)(x + (size_t)i * 4);
        half4 o;
        o[0] = (_Float16)v.x; o[1] = (_Float16)v.y; o[2] = (_Float16)v.z; o[3] = (_Float16)v.w;
        *(half4*)(xh + (size_t)i * 4) = o;
        return;
    }
    bid -= CVT_BLOCKS;
    const float* Wl; const float* Wr; _Float16* dstw; int NF, Nout, cell0;
    if (bid < 16)      { Wl = Wl0; Wr = Wr0; dstw = Wc0; NF = 8; Nout = 128; cell0 = bid * 4; }
    else if (bid < 32) { Wl = Wl1; Wr = Wr1; dstw = Wc1; NF = 8; Nout = 128; cell0 = (bid - 16) * 4; }
    else               { Wl = Wl2; Wr = Wr2; dstw = Wc2; NF = 3; Nout = 40;  cell0 = (bid - 32) * 4; }
    int cell = cell0 + (threadIdx.x >> 6);
    int t = cell / NF;
    int f = cell % NF;
    int l = threadIdx.x & 63;
    int kb = t * 32 + (l >> 4) * 8;
    int n = f * 16 + (l & 15);
    half8 v;
    #pragma unroll
    for (int i = 0; i < 8; ++i) {
        int k = kb + i;
        float w = 0.f;
        if (n < Nout) w = (k < 128) ? Wl[k * Nout + n] : Wr[(k - 128) * Nout + n];
        v[i] = (_Float16)w;
    }
    *(half8*)(dstw + ((size_t)cell * 64 + l) * 8) = v;
}

// ---------------- scans ----------------

__global__ __launch_bounds__(1024) void k_scan1(const int* __restrict__ deg, int* __restrict__ offsets,
                                                int* __restrict__ partials) {
    __shared__ int wsums[16];
    int tid = threadIdx.x;
    int g = blockIdx.x * 1024 + tid;
    int v = (g < N_NODES) ? deg[g * DEG_STRIDE] : 0;
    int lane = tid & 63;
    int wid = tid >> 6;
    int incl = v;
    #pragma unroll
    for (int off = 1; off < 64; off <<= 1) {
        int t = __shfl_up(incl, off);
        if (lane >= off) incl += t;
    }
    if (lane == 63) wsums[wid] = incl;
    __syncthreads();
    if (wid == 0) {
        int wv = (lane < 16) ? wsums[lane] : 0;
        int wincl = wv;
        #pragma unroll
        for (int off = 1; off < 16; off <<= 1) {
            int t = __shfl_up(wincl, off);
            if (lane >= off) wincl += t;
        }
        if (lane < 16) wsums[lane] = wincl - wv;
    }
    __syncthreads();
    if (g < N_NODES) offsets[g] = wsums[wid] + incl - v;
    if (tid == 1023) partials[blockIdx.x] = wsums[15] + incl;
}

__global__ __launch_bounds__(64) void k_scan2(int* __restrict__ partials, int nParts) {
    int lane = threadIdx.x;
    int v = (lane < nParts) ? partials[lane] : 0;
    int incl = v;
    #pragma unroll
    for (int off = 1; off < 64; off <<= 1) {
        int t = __shfl_up(incl, off);
        if (lane >= off) incl += t;
    }
    if (lane < nParts) partials[lane] = incl - v;
}

// scatter with inline scan3 (offsets[d] + partials[d>>10])
__global__ __launch_bounds__(256) void k_scatter(const int* __restrict__ src, const int* __restrict__ dst,
                                                 const int* __restrict__ offsets, const int* __restrict__ partials,
                                                 const unsigned short* __restrict__ rank,
                                                 unsigned short* __restrict__ sorted_src) {
    int e = blockIdx.x * 256 + threadIdx.x;
    if (e < N_EDGES) {
        int d = dst[e];
        int pos = offsets[d] + partials[d >> 10] + (int)rank[e];
        sorted_src[pos] = (unsigned short)src[e];
    }
}

// ---------------- mean aggregation: one 16-lane group per node (4 nodes/wave) ----------------

__global__ __launch_bounds__(256) void k_agg_h(const _Float16* __restrict__ feat, const int* __restrict__ offsets,
                                               const int* __restrict__ partials, const int* __restrict__ deg,
                                               const unsigned short* __restrict__ sorted_src,
                                               _Float16* __restrict__ mean) {
    int node = (int)((blockIdx.x * 256 + threadIdx.x) >> 4);
    int cl = threadIdx.x & 15;
    if (node >= N_NODES) return;
    int start = offsets[node] + partials[node >> 10];
    int cnt = deg[node * DEG_STRIDE];
    float acc[8] = {0.f, 0.f, 0.f, 0.f, 0.f, 0.f, 0.f, 0.f};
    #pragma unroll 8
    for (int e = 0; e < cnt; ++e) {
        int s = (int)sorted_src[start + e];
        half8 v = *(const half8*)(feat + (size_t)s * 128 + cl * 8);
        #pragma unroll
        for (int q = 0; q < 8; ++q) acc[q] += (float)v[q];
    }
    float r = 1.0f / (float)(cnt > 0 ? cnt : 1);
    half8 o;
    #pragma unroll
    for (int q = 0; q < 8; ++q) o[q] = (_Float16)(acc[q] * r);
    *(half8*)(mean + (size_t)node * 128 + cl * 8) = o;
}

// ---------------- hidden layer MFMA GEMM with LDS-staged A/B tiles ----------------

__global__ __launch_bounds__(256) void k_gemm_h(const _Float16* __restrict__ A, const _Float16* __restrict__ B,
                                                const _Float16* __restrict__ Wc, const float* __restrict__ bias,
                                                _Float16* __restrict__ outp) {
    __shared__ _Float16 sA[128 * 128];
    __shared__ _Float16 sB[128 * 128];
    int tid = threadIdx.x;
    int rows0 = blockIdx.x * 128;
    for (int i = 0; i < 8; ++i) {
        int cid = i * 256 + tid;
        int r = cid >> 4;
        int ch = cid & 15;
        int gr = rows0 + r;
        int grc = gr < N_NODES ? gr : N_NODES - 1;
        half8 va = *(const half8*)(A + (size_t)grc * 128 + ch * 8);
        half8 vb = *(const half8*)(B + (size_t)grc * 128 + ch * 8);
        int sch = ch ^ (r & 15);
        *(half8*)(sA + r * 128 + sch * 8) = va;
        *(half8*)(sB + r * 128 + sch * 8) = vb;
    }
    __syncthreads();
    int w = tid >> 6;
    int lane = tid & 63;
    int ln = lane & 15, lg = lane >> 4;
    int r0 = w * 32 + ln;
    int r1 = r0 + 16;
    f32x4 acc[2][8];
    #pragma unroll
    for (int i = 0; i < 2; ++i)
        #pragma unroll
        for (int f = 0; f < 8; ++f) acc[i][f] = (f32x4){0.f, 0.f, 0.f, 0.f};
    #pragma unroll
    for (int t = 0; t < 8; ++t) {
        const _Float16* P = (t < 4) ? sA : sB;
        int ch = (t & 3) * 4 + lg;
        half8 a0 = *(const half8*)(P + r0 * 128 + (ch ^ (r0 & 15)) * 8);
        half8 a1 = *(const half8*)(P + r1 * 128 + (ch ^ (r1 & 15)) * 8);
        #pragma unroll
        for (int f = 0; f < 8; ++f) {
            half8 b = *(const half8*)(Wc + ((size_t)(t * 8 + f) * 64 + lane) * 8);
            acc[0][f] = __builtin_amdgcn_mfma_f32_16x16x32_f16(a0, b, acc[0][f], 0, 0, 0);
            acc[1][f] = __builtin_amdgcn_mfma_f32_16x16x32_f16(a1, b, acc[1][f], 0, 0, 0);
        }
    }
    int rw = rows0 + w * 32;
    #pragma unroll
    for (int mf = 0; mf < 2; ++mf) {
        #pragma unroll
        for (int f = 0; f < 8; ++f) {
            int n = f * 16 + ln;
            float bv = bias[n];
            #pragma unroll
            for (int r = 0; r < 4; ++r) {
                int m = rw + mf * 16 + lg * 4 + r;
                if (m < N_NODES) {
                    float v = fmaxf(acc[mf][f][r] + bv, 0.f);
                    outp[(size_t)m * 128 + n] = (_Float16)v;
                }
            }
        }
    }
}

// ---------------- final layer MFMA GEMM (N=40 pad 48) + relu + log_softmax, LDS-staged ----------------

__global__ __launch_bounds__(256) void k_gemm_f(const _Float16* __restrict__ A, const _Float16* __restrict__ B,
                                                const _Float16* __restrict__ Wc, const float* __restrict__ bias,
                                                float* __restrict__ outp) {
    __shared__ _Float16 sA[128 * 128];
    __shared__ _Float16 sB[128 * 128];
    int tid = threadIdx.x;
    int rows0 = blockIdx.x * 128;
    for (int i = 0; i < 8; ++i) {
        int cid = i * 256 + tid;
        int r = cid >> 4;
        int ch = cid & 15;
        int gr = rows0 + r;
        int grc = gr < N_NODES ? gr : N_NODES - 1;
        half8 va = *(const half8*)(A + (size_t)grc * 128 + ch * 8);
        half8 vb = *(const half8*)(B + (size_t)grc * 128 + ch * 8);
        int sch = ch ^ (r & 15);
        *(half8*)(sA + r * 128 + sch * 8) = va;
        *(half8*)(sB + r * 128 + sch * 8) = vb;
    }
    __syncthreads();
    int w = tid >> 6;
    int lane = tid & 63;
    int ln = lane & 15, lg = lane >> 4;
    int r0 = w * 32 + ln;
    int r1 = r0 + 16;
    f32x4 acc[2][3];
    #pragma unroll
    for (int i = 0; i < 2; ++i)
        #pragma unroll
        for (int f = 0; f < 3; ++f) acc[i][f] = (f32x4){0.f, 0.f, 0.f, 0.f};
    #pragma unroll
    for (int t = 0; t < 8; ++t) {
        const _Float16* P = (t < 4) ? sA : sB;
        int ch = (t & 3) * 4 + lg;
        half8 a0 = *(const half8*)(P + r0 * 128 + (ch ^ (r0 & 15)) * 8);
        half8 a1 = *(const half8*)(P + r1 * 128 + (ch ^ (r1 & 15)) * 8);
        #pragma unroll
        for (int f = 0; f < 3; ++f) {
            half8 b = *(const half8*)(Wc + ((size_t)(t * 3 + f) * 64 + lane) * 8);
            acc[0][f] = __builtin_amdgcn_mfma_f32_16x16x32_f16(a0, b, acc[0][f], 0, 0, 0);
            acc[1][f] = __builtin_amdgcn_mfma_f32_16x16x32_f16(a1, b, acc[1][f], 0, 0, 0);
        }
    }
    float bv[3];
    #pragma unroll
    for (int f = 0; f < 3; ++f) {
        int n = f * 16 + ln;
        bv[f] = (n < N_CLASSES) ? bias[n] : 0.f;
    }
    int rw = rows0 + w * 32;
    #pragma unroll
    for (int mf = 0; mf < 2; ++mf) {
        #pragma unroll
        for (int r = 0; r < 4; ++r) {
            int m = rw + mf * 16 + lg * 4 + r;
            float v[3];
            float vmax = -INFINITY;
            #pragma unroll
            for (int f = 0; f < 3; ++f) {
                int n = f * 16 + ln;
                v[f] = fmaxf(acc[mf][f][r] + bv[f], 0.f);
                if (n < N_CLASSES) vmax = fmaxf(vmax, v[f]);
            }
            #pragma unroll
            for (int off = 1; off < 16; off <<= 1) vmax = fmaxf(vmax, __shfl_xor(vmax, off));
            float s = 0.f;
            #pragma unroll
            for (int f = 0; f < 3; ++f) {
                int n = f * 16 + ln;
                if (n < N_CLASSES) s += expf(v[f] - vmax);
            }
            #pragma unroll
            for (int off = 1; off < 16; off <<= 1) s += __shfl_xor(s, off);
            float lse = vmax + logf(s);
            if (m < N_NODES) {
                #pragma unroll
                for (int f = 0; f < 3; ++f) {
                    int n = f * 16 + ln;
                    if (n < N_CLASSES) outp[(size_t)m * N_CLASSES + n] = v[f] - lse;
                }
            }
        }
    }
}

extern "C" void kernel_launch(void* const* d_in, const int* in_sizes, int n_in,
                              void* d_out, int out_size, void* d_ws, size_t ws_size,
                              hipStream_t stream) {
    const float* x   = (const float*)d_in[0];
    const int*   ei  = (const int*)d_in[1];
    const float* Wl0 = (const float*)d_in[2];
    const float* bl0 = (const float*)d_in[3];
    const float* Wr0 = (const float*)d_in[4];
    const float* Wl1 = (const float*)d_in[5];
    const float* bl1 = (const float*)d_in[6];
    const float* Wr1 = (const float*)d_in[7];
    const float* Wl2 = (const float*)d_in[8];
    const float* bl2 = (const float*)d_in[9];
    const float* Wr2 = (const float*)d_in[10];
    float* out = (float*)d_out;

    const int* src = ei;
    const int* dst = ei + N_EDGES;

    // workspace layout
    int* offsets  = (int*)d_ws;                                  // 50016 ints
    int* deg      = offsets + 50016;                             // 50000*16 ints (padded, 3.2 MB)
    int* partials = deg + 50000 * DEG_STRIDE;                    // 64 ints
    unsigned short* rank   = (unsigned short*)(partials + 64);   // 800k u16
    unsigned short* sorted = rank + N_EDGES;                     // 800k u16
    _Float16* xh  = (_Float16*)(sorted + N_EDGES);
    _Float16* mh  = xh + (size_t)N_NODES * 128;
    _Float16* h0  = mh + (size_t)N_NODES * 128;
    _Float16* h1  = h0 + (size_t)N_NODES * 128;
    _Float16* Wc0 = h1 + (size_t)N_NODES * 128;
    _Float16* Wc1 = Wc0 + 8 * 8 * 64 * 8;
    _Float16* Wc2 = Wc1 + 8 * 8 * 64 * 8;

    hipMemsetAsync(deg, 0, 50000 * DEG_STRIDE * sizeof(int), stream);

    const int scanBlocks = (N_NODES + 1023) / 1024;
    k_build<<<EDGE_BLOCKS + CVT_BLOCKS + 38, 256, 0, stream>>>(dst, deg, rank, x, xh,
                                                               Wl0, Wr0, Wc0, Wl1, Wr1, Wc1, Wl2, Wr2, Wc2);
    k_scan1<<<scanBlocks, 1024, 0, stream>>>(deg, offsets, partials);
    k_scan2<<<1, 64, 0, stream>>>(partials, scanBlocks);
    k_scatter<<<EDGE_BLOCKS, 256, 0, stream>>>(src, dst, offsets, partials, rank, sorted);

    const int aggBlocks  = (N_NODES * 16 + 255) / 256;   // 3125
    const int gemmBlocks = (N_NODES + 127) / 128;        // 391

    // layer 0
    k_agg_h<<<aggBlocks, 256, 0, stream>>>(xh, offsets, partials, deg, sorted, mh);
    k_gemm_h<<<gemmBlocks, 256, 0, stream>>>(mh, xh, Wc0, bl0, h0);
    // layer 1
    k_agg_h<<<aggBlocks, 256, 0, stream>>>(h0, offsets, partials, deg, sorted, mh);
    k_gemm_h<<<gemmBlocks, 256, 0, stream>>>(mh, h0, Wc1, bl1, h1);
    // layer 2 + log_softmax
    k_agg_h<<<aggBlocks, 256, 0, stream>>>(h1, offsets, partials, deg, sorted, mh);
    k_gemm_f<<<gemmBlocks, 256, 0, stream>>>(mh, h1, Wc2, bl2, out);
}

// Round 12
// 276.958 us; speedup vs baseline: 1.0409x; 1.0409x over previous
//
#include <hip/hip_runtime.h>
#include <cstdint>
#include <cstddef>
#include <cmath>

#define N_NODES 50000
#define N_EDGES 800000
#define D_FEAT 128
#define HIDDEN 128
#define N_CLASSES 40

typedef _Float16 half8 __attribute__((ext_vector_type(8)));
typedef _Float16 half4 __attribute__((ext_vector_type(4)));
typedef float f32x4 __attribute__((ext_vector_type(4)));

#define HB 64                    // histogram blocks
#define EPB (N_EDGES / HB)       // 12500 edges per hist block
#define NHALF 25000              // node half-range per LDS pass
#define CVT1_BLOCKS 1563         // ceil(1600000 / 1024)

// ---------------- k_hist: [0,HB) LDS-histogram deg/rank ; then fp16 cvt ; then W swizzle ----------------

__global__ __launch_bounds__(1024) void k_hist(const int* __restrict__ dst,
                                               unsigned short* __restrict__ lrank, int* __restrict__ hist,
                                               const float* __restrict__ x, _Float16* __restrict__ xh,
                                               const float* __restrict__ Wl0, const float* __restrict__ Wr0, _Float16* __restrict__ Wc0,
                                               const float* __restrict__ Wl1, const float* __restrict__ Wr1, _Float16* __restrict__ Wc1,
                                               const float* __restrict__ Wl2, const float* __restrict__ Wr2, _Float16* __restrict__ Wc2) {
    __shared__ int cnt[NHALF];   // 100 KB
    int bid = blockIdx.x;
    int tid = threadIdx.x;
    if (bid < HB) {
        int ebase = bid * EPB;
        #pragma unroll
        for (int half = 0; half < 2; ++half) {
            int lo = half * NHALF;
            for (int i = tid; i < NHALF; i += 1024) cnt[i] = 0;
            __syncthreads();
            for (int i = tid; i < EPB; i += 1024) {
                int d = dst[ebase + i];
                int dl = d - lo;
                if ((unsigned)dl < (unsigned)NHALF) {
                    int r = atomicAdd(&cnt[dl], 1);
                    lrank[ebase + i] = (unsigned short)r;
                }
            }
            __syncthreads();
            for (int i = tid; i < NHALF; i += 1024)
                hist[(size_t)bid * N_NODES + lo + i] = cnt[i];
            __syncthreads();
        }
        return;
    }
    bid -= HB;
    if (bid < CVT1_BLOCKS) {
        int i = bid * 1024 + tid;
        if (i < N_NODES * D_FEAT / 4) {
            float4 v = *(const float4*)(x + (size_t)i * 4);
            half4 o;
            o[0] = (_Float16)v.x; o[1] = (_Float16)v.y; o[2] = (_Float16)v.z; o[3] = (_Float16)v.w;
            *(half4*)(xh + (size_t)i * 4) = o;
        }
        return;
    }
    bid -= CVT1_BLOCKS;
    int cell = bid * 16 + (tid >> 6);
    if (cell >= 152) return;
    const float* Wl; const float* Wr; _Float16* dstw; int NF, Nout, c;
    if (cell < 64)       { Wl = Wl0; Wr = Wr0; dstw = Wc0; NF = 8; Nout = 128; c = cell; }
    else if (cell < 128) { Wl = Wl1; Wr = Wr1; dstw = Wc1; NF = 8; Nout = 128; c = cell - 64; }
    else                 { Wl = Wl2; Wr = Wr2; dstw = Wc2; NF = 3; Nout = 40;  c = cell - 128; }
    int t = c / NF;
    int f = c % NF;
    int l = tid & 63;
    int kb = t * 32 + (l >> 4) * 8;
    int n = f * 16 + (l & 15);
    half8 v;
    #pragma unroll
    for (int i = 0; i < 8; ++i) {
        int k = kb + i;
        float w = 0.f;
        if (n < Nout) w = (k < 128) ? Wl[k * Nout + n] : Wr[(k - 128) * Nout + n];
        v[i] = (_Float16)w;
    }
    *(half8*)(dstw + ((size_t)c * 64 + l) * 8) = v;
}

// ---------------- k_colscan: per-node exclusive scan over hist rows -> block prefixes + deg ----------------

__global__ __launch_bounds__(1024) void k_colscan(int* __restrict__ hist, int* __restrict__ deg) {
    int n = blockIdx.x * 1024 + threadIdx.x;
    if (n >= N_NODES) return;
    int sum = 0;
    #pragma unroll 8
    for (int b = 0; b < HB; ++b) {
        size_t idx = (size_t)b * N_NODES + n;
        int v = hist[idx];
        hist[idx] = sum;
        sum += v;
    }
    deg[n] = sum;
}

// ---------------- scans ----------------

__global__ __launch_bounds__(1024) void k_scan1(const int* __restrict__ deg, int* __restrict__ offsets,
                                                int* __restrict__ partials) {
    __shared__ int wsums[16];
    int tid = threadIdx.x;
    int g = blockIdx.x * 1024 + tid;
    int v = (g < N_NODES) ? deg[g] : 0;
    int lane = tid & 63;
    int wid = tid >> 6;
    int incl = v;
    #pragma unroll
    for (int off = 1; off < 64; off <<= 1) {
        int t = __shfl_up(incl, off);
        if (lane >= off) incl += t;
    }
    if (lane == 63) wsums[wid] = incl;
    __syncthreads();
    if (wid == 0) {
        int wv = (lane < 16) ? wsums[lane] : 0;
        int wincl = wv;
        #pragma unroll
        for (int off = 1; off < 16; off <<= 1) {
            int t = __shfl_up(wincl, off);
            if (lane >= off) wincl += t;
        }
        if (lane < 16) wsums[lane] = wincl - wv;
    }
    __syncthreads();
    if (g < N_NODES) offsets[g] = wsums[wid] + incl - v;
    if (tid == 1023) partials[blockIdx.x] = wsums[15] + incl;
}

__global__ __launch_bounds__(64) void k_scan2(int* __restrict__ partials, int nParts) {
    int lane = threadIdx.x;
    int v = (lane < nParts) ? partials[lane] : 0;
    int incl = v;
    #pragma unroll
    for (int off = 1; off < 64; off <<= 1) {
        int t = __shfl_up(incl, off);
        if (lane >= off) incl += t;
    }
    if (lane < nParts) partials[lane] = incl - v;
}

// ---------------- scatter: pos = offsets + partials + block-prefix + local rank (no atomics) ----------------

__global__ __launch_bounds__(256) void k_scatter(const int* __restrict__ src, const int* __restrict__ dst,
                                                 const int* __restrict__ offsets, const int* __restrict__ partials,
                                                 const int* __restrict__ hist,
                                                 const unsigned short* __restrict__ lrank,
                                                 unsigned short* __restrict__ sorted_src) {
    int e = blockIdx.x * 256 + threadIdx.x;
    if (e < N_EDGES) {
        int d = dst[e];
        int b = e / EPB;
        int pos = offsets[d] + partials[d >> 10] + hist[(size_t)b * N_NODES + d] + (int)lrank[e];
        sorted_src[pos] = (unsigned short)src[e];
    }
}

// ---------------- mean aggregation: one 16-lane group per node (4 nodes/wave) ----------------

__global__ __launch_bounds__(256) void k_agg_h(const _Float16* __restrict__ feat, const int* __restrict__ offsets,
                                               const int* __restrict__ partials, const int* __restrict__ deg,
                                               const unsigned short* __restrict__ sorted_src,
                                               _Float16* __restrict__ mean) {
    int node = (int)((blockIdx.x * 256 + threadIdx.x) >> 4);
    int cl = threadIdx.x & 15;
    if (node >= N_NODES) return;
    int start = offsets[node] + partials[node >> 10];
    int cnt = deg[node];
    float acc[8] = {0.f, 0.f, 0.f, 0.f, 0.f, 0.f, 0.f, 0.f};
    #pragma unroll 8
    for (int e = 0; e < cnt; ++e) {
        int s = (int)sorted_src[start + e];
        half8 v = *(const half8*)(feat + (size_t)s * 128 + cl * 8);
        #pragma unroll
        for (int q = 0; q < 8; ++q) acc[q] += (float)v[q];
    }
    float r = 1.0f / (float)(cnt > 0 ? cnt : 1);
    half8 o;
    #pragma unroll
    for (int q = 0; q < 8; ++q) o[q] = (_Float16)(acc[q] * r);
    *(half8*)(mean + (size_t)node * 128 + cl * 8) = o;
}

// ---------------- hidden layer MFMA GEMM with LDS-staged A/B tiles ----------------

__global__ __launch_bounds__(256) void k_gemm_h(const _Float16* __restrict__ A, const _Float16* __restrict__ B,
                                                const _Float16* __restrict__ Wc, const float* __restrict__ bias,
                                                _Float16* __restrict__ outp) {
    __shared__ _Float16 sA[128 * 128];
    __shared__ _Float16 sB[128 * 128];
    int tid = threadIdx.x;
    int rows0 = blockIdx.x * 128;
    for (int i = 0; i < 8; ++i) {
        int cid = i * 256 + tid;
        int r = cid >> 4;
        int ch = cid & 15;
        int gr = rows0 + r;
        int grc = gr < N_NODES ? gr : N_NODES - 1;
        half8 va = *(const half8*)(A + (size_t)grc * 128 + ch * 8);
        half8 vb = *(const half8*)(B + (size_t)grc * 128 + ch * 8);
        int sch = ch ^ (r & 15);
        *(half8*)(sA + r * 128 + sch * 8) = va;
        *(half8*)(sB + r * 128 + sch * 8) = vb;
    }
    __syncthreads();
    int w = tid >> 6;
    int lane = tid & 63;
    int ln = lane & 15, lg = lane >> 4;
    int r0 = w * 32 + ln;
    int r1 = r0 + 16;
    f32x4 acc[2][8];
    #pragma unroll
    for (int i = 0; i < 2; ++i)
        #pragma unroll
        for (int f = 0; f < 8; ++f) acc[i][f] = (f32x4){0.f, 0.f, 0.f, 0.f};
    #pragma unroll
    for (int t = 0; t < 8; ++t) {
        const _Float16* P = (t < 4) ? sA : sB;
        int ch = (t & 3) * 4 + lg;
        half8 a0 = *(const half8*)(P + r0 * 128 + (ch ^ (r0 & 15)) * 8);
        half8 a1 = *(const half8*)(P + r1 * 128 + (ch ^ (r1 & 15)) * 8);
        #pragma unroll
        for (int f = 0; f < 8; ++f) {
            half8 b = *(const half8*)(Wc + ((size_t)(t * 8 + f) * 64 + lane) * 8);
            acc[0][f] = __builtin_amdgcn_mfma_f32_16x16x32_f16(a0, b, acc[0][f], 0, 0, 0);
            acc[1][f] = __builtin_amdgcn_mfma_f32_16x16x32_f16(a1, b, acc[1][f], 0, 0, 0);
        }
    }
    int rw = rows0 + w * 32;
    #pragma unroll
    for (int mf = 0; mf < 2; ++mf) {
        #pragma unroll
        for (int f = 0; f < 8; ++f) {
            int n = f * 16 + ln;
            float bv = bias[n];
            #pragma unroll
            for (int r = 0; r < 4; ++r) {
                int m = rw + mf * 16 + lg * 4 + r;
                if (m < N_NODES) {
                    float v = fmaxf(acc[mf][f][r] + bv, 0.f);
                    outp[(size_t)m * 128 + n] = (_Float16)v;
                }
            }
        }
    }
}

// ---------------- final layer MFMA GEMM (N=40 pad 48) + relu + log_softmax, LDS-staged ----------------

__global__ __launch_bounds__(256) void k_gemm_f(const _Float16* __restrict__ A, const _Float16* __restrict__ B,
                                                const _Float16* __restrict__ Wc, const float* __restrict__ bias,
                                                float* __restrict__ outp) {
    __shared__ _Float16 sA[128 * 128];
    __shared__ _Float16 sB[128 * 128];
    int tid = threadIdx.x;
    int rows0 = blockIdx.x * 128;
    for (int i = 0; i < 8; ++i) {
        int cid = i * 256 + tid;
        int r = cid >> 4;
        int ch = cid & 15;
        int gr = rows0 + r;
        int grc = gr < N_NODES ? gr : N_NODES - 1;
        half8 va = *(const half8*)(A + (size_t)grc * 128 + ch * 8);
        half8 vb = *(const half8*)(B + (size_t)grc * 128 + ch * 8);
        int sch = ch ^ (r & 15);
        *(half8*)(sA + r * 128 + sch * 8) = va;
        *(half8*)(sB + r * 128 + sch * 8) = vb;
    }
    __syncthreads();
    int w = tid >> 6;
    int lane = tid & 63;
    int ln = lane & 15, lg = lane >> 4;
    int r0 = w * 32 + ln;
    int r1 = r0 + 16;
    f32x4 acc[2][3];
    #pragma unroll
    for (int i = 0; i < 2; ++i)
        #pragma unroll
        for (int f = 0; f < 3; ++f) acc[i][f] = (f32x4){0.f, 0.f, 0.f, 0.f};
    #pragma unroll
    for (int t = 0; t < 8; ++t) {
        const _Float16* P = (t < 4) ? sA : sB;
        int ch = (t & 3) * 4 + lg;
        half8 a0 = *(const half8*)(P + r0 * 128 + (ch ^ (r0 & 15)) * 8);
        half8 a1 = *(const half8*)(P + r1 * 128 + (ch ^ (r1 & 15)) * 8);
        #pragma unroll
        for (int f = 0; f < 3; ++f) {
            half8 b = *(const half8*)(Wc + ((size_t)(t * 3 + f) * 64 + lane) * 8);
            acc[0][f] = __builtin_amdgcn_mfma_f32_16x16x32_f16(a0, b, acc[0][f], 0, 0, 0);
            acc[1][f] = __builtin_amdgcn_mfma_f32_16x16x32_f16(a1, b, acc[1][f], 0, 0, 0);
        }
    }
    float bv[3];
    #pragma unroll
    for (int f = 0; f < 3; ++f) {
        int n = f * 16 + ln;
        bv[f] = (n < N_CLASSES) ? bias[n] : 0.f;
    }
    int rw = rows0 + w * 32;
    #pragma unroll
    for (int mf = 0; mf < 2; ++mf) {
        #pragma unroll
        for (int r = 0; r < 4; ++r) {
            int m = rw + mf * 16 + lg * 4 + r;
            float v[3];
            float vmax = -INFINITY;
            #pragma unroll
            for (int f = 0; f < 3; ++f) {
                int n = f * 16 + ln;
                v[f] = fmaxf(acc[mf][f][r] + bv[f], 0.f);
                if (n < N_CLASSES) vmax = fmaxf(vmax, v[f]);
            }
            #pragma unroll
            for (int off = 1; off < 16; off <<= 1) vmax = fmaxf(vmax, __shfl_xor(vmax, off));
            float s = 0.f;
            #pragma unroll
            for (int f = 0; f < 3; ++f) {
                int n = f * 16 + ln;
                if (n < N_CLASSES) s += expf(v[f] - vmax);
            }
            #pragma unroll
            for (int off = 1; off < 16; off <<= 1) s += __shfl_xor(s, off);
            float lse = vmax + logf(s);
            if (m < N_NODES) {
                #pragma unroll
                for (int f = 0; f < 3; ++f) {
                    int n = f * 16 + ln;
                    if (n < N_CLASSES) outp[(size_t)m * N_CLASSES + n] = v[f] - lse;
                }
            }
        }
    }
}

extern "C" void kernel_launch(void* const* d_in, const int* in_sizes, int n_in,
                              void* d_out, int out_size, void* d_ws, size_t ws_size,
                              hipStream_t stream) {
    const float* x   = (const float*)d_in[0];
    const int*   ei  = (const int*)d_in[1];
    const float* Wl0 = (const float*)d_in[2];
    const float* bl0 = (const float*)d_in[3];
    const float* Wr0 = (const float*)d_in[4];
    const float* Wl1 = (const float*)d_in[5];
    const float* bl1 = (const float*)d_in[6];
    const float* Wr1 = (const float*)d_in[7];
    const float* Wl2 = (const float*)d_in[8];
    const float* bl2 = (const float*)d_in[9];
    const float* Wr2 = (const float*)d_in[10];
    float* out = (float*)d_out;

    const int* src = ei;
    const int* dst = ei + N_EDGES;

    // workspace layout (no zero-init required anywhere)
    int* offsets  = (int*)d_ws;                                  // 50016 ints
    int* deg      = offsets + 50016;                             // 50016 ints
    int* partials = deg + 50016;                                 // 64 ints
    int* hist     = partials + 64;                               // 64 * 50000 ints (12.8 MB)
    unsigned short* lrank  = (unsigned short*)(hist + HB * N_NODES);  // 800k u16
    unsigned short* sorted = lrank + N_EDGES;                    // 800k u16
    _Float16* xh  = (_Float16*)(sorted + N_EDGES);
    _Float16* mh  = xh + (size_t)N_NODES * 128;
    _Float16* h0  = mh + (size_t)N_NODES * 128;
    _Float16* h1  = h0 + (size_t)N_NODES * 128;
    _Float16* Wc0 = h1 + (size_t)N_NODES * 128;
    _Float16* Wc1 = Wc0 + 8 * 8 * 64 * 8;
    _Float16* Wc2 = Wc1 + 8 * 8 * 64 * 8;

    const int histGrid = HB + CVT1_BLOCKS + 10;   // 64 + 1563 + 10 (152 swizzle cells / 16 per block)
    const int scanBlocks = (N_NODES + 1023) / 1024;

    k_hist<<<histGrid, 1024, 0, stream>>>(dst, lrank, hist, x, xh,
                                          Wl0, Wr0, Wc0, Wl1, Wr1, Wc1, Wl2, Wr2, Wc2);
    k_colscan<<<scanBlocks, 1024, 0, stream>>>(hist, deg);
    k_scan1<<<scanBlocks, 1024, 0, stream>>>(deg, offsets, partials);
    k_scan2<<<1, 64, 0, stream>>>(partials, scanBlocks);
    k_scatter<<<(N_EDGES + 255) / 256, 256, 0, stream>>>(src, dst, offsets, partials, hist, lrank, sorted);

    const int aggBlocks  = (N_NODES * 16 + 255) / 256;   // 3125
    const int gemmBlocks = (N_NODES + 127) / 128;        // 391

    // layer 0
    k_agg_h<<<aggBlocks, 256, 0, stream>>>(xh, offsets, partials, deg, sorted, mh);
    k_gemm_h<<<gemmBlocks, 256, 0, stream>>>(mh, xh, Wc0, bl0, h0);
    // layer 1
    k_agg_h<<<aggBlocks, 256, 0, stream>>>(h0, offsets, partials, deg, sorted, mh);
    k_gemm_h<<<gemmBlocks, 256, 0, stream>>>(mh, h0, Wc1, bl1, h1);
    // layer 2 + log_softmax
    k_agg_h<<<aggBlocks, 256, 0, stream>>>(h1, offsets, partials, deg, sorted, mh);
    k_gemm_f<<<gemmBlocks, 256, 0, stream>>>(mh, h1, Wc2, bl2, out);
}